// Round 8
// baseline (178.159 us; speedup 1.0000x reference)
//
#include <hip/hip_runtime.h>

#define NN 50000
#define NE 1600000
#define D 128
#define RPB 16       // rows (nodes) per fused gather+gemm block
#define NR 2         // key ranges (node-id partitions)
#define RNG 25000    // NN / NR keys per range
#define NC 32        // src edge chunks (CHUNK = 50000)
#define CHUNK 50000
#define NC2 64       // dst edge chunks (CHUNK2 = 25000)
#define CHUNK2 25000
#define NB 49        // scan blocks = ceil(NN/1024)

// ---- workspace layout (bytes), total 19,879,936 (proven budget) ----
#define WS_INV  0         // float NN
#define WS_CNT  204800    // int NN   (dst degree)
#define WS_OFF  409600    // int NN   (CSR offsets)
#define WS_BSUM 610304    // int NB
#define WS_WT   614400    // float 128*128
#define WS_PDST 679936    // int NR*NC2*RNG = 12.8 MB (dst counts -> absolute bases)
#define WS_PSRC 13479936  // ushort NR*NC*RNG = 3.2 MB (src counts)
#define WS_CSR  16679936  // ushort NE = 3.2 MB
#define WS_XNB  679936    // ushort NN*128 = 12.8 MB, OVERWRITES pdst after fill_sorted

// ---------------- fused: src hist (64 blks) + dst hist (128 blks) + W transpose (16 blks) ----------------
__global__ __launch_bounds__(1024) void fused_pre(const int* __restrict__ ei,
                                                  const float* __restrict__ W,
                                                  unsigned short* __restrict__ psrc,
                                                  int* __restrict__ pdst,
                                                  float* __restrict__ Wt) {
    __shared__ int h[RNG];
    int bid = blockIdx.x;
    if (bid < 64) {
        int r = bid >> 5, c = bid & 31;
        int lo = r * RNG;
        for (int j = threadIdx.x; j < RNG; j += 1024) h[j] = 0;
        __syncthreads();
        const int* s = ei + c * CHUNK;
        for (int i = threadIdx.x; i < CHUNK; i += 1024) {
            int k = s[i] - lo;
            if ((unsigned)k < RNG) atomicAdd(&h[k], 1);
        }
        __syncthreads();
        unsigned short* p = psrc + (size_t)bid * RNG;
        for (int j = threadIdx.x; j < RNG; j += 1024) p[j] = (unsigned short)h[j];
    } else if (bid < 192) {
        int b2 = bid - 64;
        int r = b2 >> 6, c = b2 & 63;
        int lo = r * RNG;
        for (int j = threadIdx.x; j < RNG; j += 1024) h[j] = 0;
        __syncthreads();
        const int* d = ei + NE + c * CHUNK2;
        for (int i = threadIdx.x; i < CHUNK2; i += 1024) {
            int k = d[i] - lo;
            if ((unsigned)k < RNG) atomicAdd(&h[k], 1);
        }
        __syncthreads();
        int* p = pdst + (size_t)b2 * RNG;
        for (int j = threadIdx.x; j < RNG; j += 1024) p[j] = h[j];
    } else {
        int i = (bid - 192) * 1024 + threadIdx.x;
        int c = i >> 7, k = i & 127;
        Wt[k * D + c] = W[i];
    }
}

// ---------------- inv[k] = rsqrt(src_deg+1); cnt[k] = dst_deg ----------------
__global__ void reduce_both(const unsigned short* __restrict__ psrc,
                            const int* __restrict__ pdst,
                            float* __restrict__ inv, int* __restrict__ cnt) {
    int k = blockIdx.x * blockDim.x + threadIdx.x;
    if (k >= NN) return;
    int r = k / RNG, j = k - r * RNG;
    size_t bs = (size_t)(r * NC) * RNG + j;
    int s = 0;
#pragma unroll 8
    for (int c = 0; c < NC; ++c) s += psrc[bs + (size_t)c * RNG];
    size_t bd = (size_t)(r * NC2) * RNG + j;
    int t = 0;
#pragma unroll 8
    for (int c = 0; c < NC2; ++c) t += pdst[bd + (size_t)c * RNG];
    inv[k] = rsqrtf((float)s + 1.0f);
    cnt[k] = t;
}

// ---------------- phase 1: per-1024-block exclusive scan of cnt ----------------
__global__ __launch_bounds__(1024) void scan_blocks(const int* __restrict__ cnt,
                                                    int* __restrict__ off,
                                                    int* __restrict__ bsum) {
    __shared__ int s[1024];
    int tid = threadIdx.x;
    int i = blockIdx.x * 1024 + tid;
    int v = (i < NN) ? cnt[i] : 0;
    s[tid] = v;
    __syncthreads();
    for (int d = 1; d < 1024; d <<= 1) {
        int t = (tid >= d) ? s[tid - d] : 0;
        __syncthreads();
        s[tid] += t;
        __syncthreads();
    }
    if (i < NN) off[i] = s[tid] - v;  // exclusive within block
    if (tid == 1023) bsum[blockIdx.x] = s[1023];
}

// ---------------- phase 2+3: add block base; pdst counts -> absolute CSR bases ----------------
__global__ void scan_chunks(int* __restrict__ pdst, int* __restrict__ off,
                            const int* __restrict__ bsum) {
    int k = blockIdx.x * blockDim.x + threadIdx.x;
    if (k >= NN) return;
    int bi = k >> 10;
    int top = 0;
#pragma unroll 8
    for (int c = 0; c < bi; ++c) top += bsum[c];
    int run = off[k] + top;
    off[k] = run;  // final CSR offset
    int r = k / RNG, j = k - r * RNG;
    size_t base = (size_t)(r * NC2) * RNG + j;
#pragma unroll 8
    for (int c = 0; c < NC2; ++c) {
        size_t p = base + (size_t)c * RNG;
        int v = pdst[p];
        pdst[p] = run;
        run += v;
    }
}

// ---------------- place edges: LDS cursor atomics only, plain ushort CSR stores ----------------
__global__ __launch_bounds__(1024) void fill_sorted(const int* __restrict__ ei,
                                                    const int* __restrict__ bases,
                                                    unsigned short* __restrict__ csr) {
    __shared__ int cur[RNG];
    int r = blockIdx.x >> 6, c = blockIdx.x & 63;
    int lo = r * RNG;
    const int* bslice = bases + (size_t)blockIdx.x * RNG;
    for (int j = threadIdx.x; j < RNG; j += 1024) cur[j] = bslice[j];
    __syncthreads();
    const int* s = ei + c * CHUNK2;
    const int* d = ei + NE + c * CHUNK2;
    for (int i = threadIdx.x; i < CHUNK2; i += 1024) {
        int kd = d[i] - lo;
        if ((unsigned)kd < RNG) {
            int pos = atomicAdd(&cur[kd], 1);
            csr[pos] = (unsigned short)s[i];
        }
    }
}

// ---------------- xnb[n][c] = bf16_rne(x[n][c] * inv[n]), packed 2/u32 ----------------
__device__ __forceinline__ unsigned bf16_rne(float f) {
    unsigned u = __float_as_uint(f);
    return (u + 0x7fffu + ((u >> 16) & 1u)) >> 16;
}
__global__ void scale_kernel(const float* __restrict__ x, const float* __restrict__ inv,
                             unsigned* __restrict__ xnb4) {
    int i = blockIdx.x * blockDim.x + threadIdx.x;  // 0 .. NN*16-1
    if (i >= NN * 16) return;
    int row = i >> 4;
    float w = inv[row];
    const float4* src = (const float4*)(x + (size_t)i * 8);
    float4 a = src[0], bq = src[1];
    uint4 o;
    o.x = bf16_rne(a.x * w)  | (bf16_rne(a.y * w) << 16);
    o.y = bf16_rne(a.z * w)  | (bf16_rne(a.w * w) << 16);
    o.z = bf16_rne(bq.x * w) | (bf16_rne(bq.y * w) << 16);
    o.w = bf16_rne(bq.z * w) | (bf16_rne(bq.w * w) << 16);
    ((uint4*)xnb4)[i] = o;
}

// ---------------- fused gather + GEMM ----------------
// 1024 threads = 16 waves; wave w gathers node r0+w into LDS h[w][:]
// then the whole block does out[r][c] = h[r][:].Wt[:][c] + b[c]
__global__ __launch_bounds__(1024) void gather_gemm(const unsigned* __restrict__ xnb,
                                                    const float* __restrict__ inv,
                                                    const int* __restrict__ off,
                                                    const int* __restrict__ cnt,
                                                    const unsigned short* __restrict__ csr,
                                                    const float* __restrict__ Wt,
                                                    const float* __restrict__ b,
                                                    float* __restrict__ out) {
    __shared__ float h[RPB][D];
    int r0 = blockIdx.x * RPB;
    int tid = threadIdx.x;
    int widx = tid >> 6;         // wave index in block = row index
    int wid = r0 + widx;         // node id
    int lane = tid & 63;
    int half = lane >> 5;
    int col4 = lane & 31;        // owns cols 4*col4 .. 4*col4+3

    // ---- gather phase: one wave per node, lanes 0-31 even edges, 32-63 odd ----
    float ax = 0.f, ay = 0.f, az = 0.f, aw = 0.f;
    const uint2* xb = (const uint2*)xnb;  // 32 uint2 per row
    if (half == 0) {
        uint2 u = xb[(size_t)wid * 32 + col4];
        ax = __uint_as_float(u.x << 16);
        ay = __uint_as_float(u.x & 0xffff0000u);
        az = __uint_as_float(u.y << 16);
        aw = __uint_as_float(u.y & 0xffff0000u);
    }
    int n = cnt[wid];
    const unsigned short* row = csr + off[wid];
    int i = half;
    for (; i + 6 < n; i += 8) {
        int s0 = row[i], s1 = row[i + 2], s2 = row[i + 4], s3 = row[i + 6];
        uint2 u0 = xb[(size_t)s0 * 32 + col4];
        uint2 u1 = xb[(size_t)s1 * 32 + col4];
        uint2 u2 = xb[(size_t)s2 * 32 + col4];
        uint2 u3 = xb[(size_t)s3 * 32 + col4];
        ax += __uint_as_float(u0.x << 16) + __uint_as_float(u1.x << 16)
            + __uint_as_float(u2.x << 16) + __uint_as_float(u3.x << 16);
        ay += __uint_as_float(u0.x & 0xffff0000u) + __uint_as_float(u1.x & 0xffff0000u)
            + __uint_as_float(u2.x & 0xffff0000u) + __uint_as_float(u3.x & 0xffff0000u);
        az += __uint_as_float(u0.y << 16) + __uint_as_float(u1.y << 16)
            + __uint_as_float(u2.y << 16) + __uint_as_float(u3.y << 16);
        aw += __uint_as_float(u0.y & 0xffff0000u) + __uint_as_float(u1.y & 0xffff0000u)
            + __uint_as_float(u2.y & 0xffff0000u) + __uint_as_float(u3.y & 0xffff0000u);
    }
    for (; i < n; i += 2) {
        int s = row[i];
        uint2 u = xb[(size_t)s * 32 + col4];
        ax += __uint_as_float(u.x << 16);
        ay += __uint_as_float(u.x & 0xffff0000u);
        az += __uint_as_float(u.y << 16);
        aw += __uint_as_float(u.y & 0xffff0000u);
    }
    ax += __shfl_xor(ax, 32, 64);
    ay += __shfl_xor(ay, 32, 64);
    az += __shfl_xor(az, 32, 64);
    aw += __shfl_xor(aw, 32, 64);
    if (half == 0) {
        float wn = inv[wid];
        float4 o;
        o.x = ax * wn; o.y = ay * wn; o.z = az * wn; o.w = aw * wn;
        *(float4*)&h[widx][col4 * 4] = o;
    }
    __syncthreads();

    // ---- GEMM phase: 8 groups of 128 cols; group g owns rows 2g, 2g+1 ----
    int c = tid & 127;
    int g = tid >> 7;
    float acc0 = 0.f, acc1 = 0.f;
    const float* hr0 = h[g * 2];
    const float* hr1 = h[g * 2 + 1];
    for (int k0 = 0; k0 < D; k0 += 4) {
        float w0 = Wt[(k0 + 0) * D + c];
        float w1 = Wt[(k0 + 1) * D + c];
        float w2 = Wt[(k0 + 2) * D + c];
        float w3 = Wt[(k0 + 3) * D + c];
        float4 h0 = *(const float4*)&hr0[k0];  // LDS broadcast
        float4 h1 = *(const float4*)&hr1[k0];
        acc0 += h0.x * w0 + h0.y * w1 + h0.z * w2 + h0.w * w3;
        acc1 += h1.x * w0 + h1.y * w1 + h1.z * w2 + h1.w * w3;
    }
    float bc = b[c];
    out[(size_t)(r0 + g * 2) * D + c]     = acc0 + bc;
    out[(size_t)(r0 + g * 2 + 1) * D + c] = acc1 + bc;
}

extern "C" void kernel_launch(void* const* d_in, const int* in_sizes, int n_in,
                              void* d_out, int out_size, void* d_ws, size_t ws_size,
                              hipStream_t stream) {
    const float* x  = (const float*)d_in[0];
    const int*   ei = (const int*)d_in[1];
    const float* W  = (const float*)d_in[2];
    const float* b  = (const float*)d_in[3];
    float* out = (float*)d_out;

    char* ws = (char*)d_ws;
    float*          inv  = (float*)         (ws + WS_INV);
    int*            cnt  = (int*)           (ws + WS_CNT);
    int*            off  = (int*)           (ws + WS_OFF);
    int*            bsum = (int*)           (ws + WS_BSUM);
    float*          Wt   = (float*)         (ws + WS_WT);
    int*            pdst = (int*)           (ws + WS_PDST);
    unsigned short* psrc = (unsigned short*)(ws + WS_PSRC);
    unsigned short* csr  = (unsigned short*)(ws + WS_CSR);
    unsigned*       xnb  = (unsigned*)      (ws + WS_XNB);  // overlays pdst AFTER fill_sorted

    fused_pre<<<208, 1024, 0, stream>>>(ei, W, psrc, pdst, Wt);
    reduce_both<<<(NN + 255) / 256, 256, 0, stream>>>(psrc, pdst, inv, cnt);
    scan_blocks<<<NB, 1024, 0, stream>>>(cnt, off, bsum);
    scan_chunks<<<(NN + 255) / 256, 256, 0, stream>>>(pdst, off, bsum);
    fill_sorted<<<NR * NC2, 1024, 0, stream>>>(ei, pdst, csr);
    scale_kernel<<<(NN * 16 + 255) / 256, 256, 0, stream>>>(x, inv, xnb);
    gather_gemm<<<NN / RPB, 1024, 0, stream>>>(xnb, inv, off, cnt, csr, Wt, b, out);
}

// Round 9
// 166.929 us; speedup vs baseline: 1.0673x; 1.0673x over previous
//
#include <hip/hip_runtime.h>

#define NN 50000
#define NE 1600000
#define D 128
#define RPB 40       // rows per block in the GEMM epilogue (50000/40 = 1250 blocks)
#define NR 2         // key ranges (node-id partitions)
#define RNG 25000    // NN / NR keys per range
#define NC 32        // src edge chunks (CHUNK = 50000)
#define CHUNK 50000
#define NC2 64       // dst edge chunks (CHUNK2 = 25000)
#define CHUNK2 25000
#define NB 49        // scan blocks = ceil(NN/1024)

// ---- workspace layout (bytes), total 19,879,936 (proven budget) ----
#define WS_INV  0         // float NN
#define WS_CNT  204800    // int NN   (dst degree)
#define WS_OFF  409600    // int NN   (CSR offsets)
#define WS_BSUM 610304    // int NB
#define WS_WT   614400    // float 128*128
#define WS_PDST 679936    // int NR*NC2*RNG = 12.8 MB (dst counts -> absolute bases)
#define WS_PSRC 13479936  // ushort NR*NC*RNG = 3.2 MB (src counts)
#define WS_CSR  16679936  // ushort NE = 3.2 MB
#define WS_XNB  679936    // ushort NN*128 = 12.8 MB, OVERWRITES pdst after fill_sorted

// ---------------- fused: src hist (64 blks) + dst hist (128 blks) + W transpose (16 blks) ----------------
__global__ __launch_bounds__(1024) void fused_pre(const int* __restrict__ ei,
                                                  const float* __restrict__ W,
                                                  unsigned short* __restrict__ psrc,
                                                  int* __restrict__ pdst,
                                                  float* __restrict__ Wt) {
    __shared__ int h[RNG];
    int bid = blockIdx.x;
    if (bid < 64) {
        int r = bid >> 5, c = bid & 31;
        int lo = r * RNG;
        for (int j = threadIdx.x; j < RNG; j += 1024) h[j] = 0;
        __syncthreads();
        const int* s = ei + c * CHUNK;
        for (int i = threadIdx.x; i < CHUNK; i += 1024) {
            int k = s[i] - lo;
            if ((unsigned)k < RNG) atomicAdd(&h[k], 1);
        }
        __syncthreads();
        unsigned short* p = psrc + (size_t)bid * RNG;
        for (int j = threadIdx.x; j < RNG; j += 1024) p[j] = (unsigned short)h[j];
    } else if (bid < 192) {
        int b2 = bid - 64;
        int r = b2 >> 6, c = b2 & 63;
        int lo = r * RNG;
        for (int j = threadIdx.x; j < RNG; j += 1024) h[j] = 0;
        __syncthreads();
        const int* d = ei + NE + c * CHUNK2;
        for (int i = threadIdx.x; i < CHUNK2; i += 1024) {
            int k = d[i] - lo;
            if ((unsigned)k < RNG) atomicAdd(&h[k], 1);
        }
        __syncthreads();
        int* p = pdst + (size_t)b2 * RNG;
        for (int j = threadIdx.x; j < RNG; j += 1024) p[j] = h[j];
    } else {
        int i = (bid - 192) * 1024 + threadIdx.x;
        int c = i >> 7, k = i & 127;
        Wt[k * D + c] = W[i];
    }
}

// ---------------- inv[k] = rsqrt(src_deg+1); cnt[k] = dst_deg ----------------
__global__ void reduce_both(const unsigned short* __restrict__ psrc,
                            const int* __restrict__ pdst,
                            float* __restrict__ inv, int* __restrict__ cnt) {
    int k = blockIdx.x * blockDim.x + threadIdx.x;
    if (k >= NN) return;
    int r = k / RNG, j = k - r * RNG;
    size_t bs = (size_t)(r * NC) * RNG + j;
    int s = 0;
#pragma unroll 8
    for (int c = 0; c < NC; ++c) s += psrc[bs + (size_t)c * RNG];
    size_t bd = (size_t)(r * NC2) * RNG + j;
    int t = 0;
#pragma unroll 8
    for (int c = 0; c < NC2; ++c) t += pdst[bd + (size_t)c * RNG];
    inv[k] = rsqrtf((float)s + 1.0f);
    cnt[k] = t;
}

// ---------------- phase 1: per-1024-block exclusive scan of cnt ----------------
__global__ __launch_bounds__(1024) void scan_blocks(const int* __restrict__ cnt,
                                                    int* __restrict__ off,
                                                    int* __restrict__ bsum) {
    __shared__ int s[1024];
    int tid = threadIdx.x;
    int i = blockIdx.x * 1024 + tid;
    int v = (i < NN) ? cnt[i] : 0;
    s[tid] = v;
    __syncthreads();
    for (int d = 1; d < 1024; d <<= 1) {
        int t = (tid >= d) ? s[tid - d] : 0;
        __syncthreads();
        s[tid] += t;
        __syncthreads();
    }
    if (i < NN) off[i] = s[tid] - v;  // exclusive within block
    if (tid == 1023) bsum[blockIdx.x] = s[1023];
}

// ---------------- phase 2+3: add block base; pdst counts -> absolute CSR bases ----------------
__global__ void scan_chunks(int* __restrict__ pdst, int* __restrict__ off,
                            const int* __restrict__ bsum) {
    int k = blockIdx.x * blockDim.x + threadIdx.x;
    if (k >= NN) return;
    int bi = k >> 10;
    int top = 0;
#pragma unroll 8
    for (int c = 0; c < bi; ++c) top += bsum[c];
    int run = off[k] + top;
    off[k] = run;  // final CSR offset
    int r = k / RNG, j = k - r * RNG;
    size_t base = (size_t)(r * NC2) * RNG + j;
#pragma unroll 8
    for (int c = 0; c < NC2; ++c) {
        size_t p = base + (size_t)c * RNG;
        int v = pdst[p];
        pdst[p] = run;
        run += v;
    }
}

// ---------------- place edges: LDS cursor atomics only, plain ushort CSR stores ----------------
__global__ __launch_bounds__(1024) void fill_sorted(const int* __restrict__ ei,
                                                    const int* __restrict__ bases,
                                                    unsigned short* __restrict__ csr) {
    __shared__ int cur[RNG];
    int r = blockIdx.x >> 6, c = blockIdx.x & 63;
    int lo = r * RNG;
    const int* bslice = bases + (size_t)blockIdx.x * RNG;
    for (int j = threadIdx.x; j < RNG; j += 1024) cur[j] = bslice[j];
    __syncthreads();
    const int* s = ei + c * CHUNK2;
    const int* d = ei + NE + c * CHUNK2;
    for (int i = threadIdx.x; i < CHUNK2; i += 1024) {
        int kd = d[i] - lo;
        if ((unsigned)kd < RNG) {
            int pos = atomicAdd(&cur[kd], 1);
            csr[pos] = (unsigned short)s[i];
        }
    }
}

// ---------------- xnb[n][c] = bf16_rne(x[n][c] * inv[n]), packed 2/u32 ----------------
__device__ __forceinline__ unsigned bf16_rne(float f) {
    unsigned u = __float_as_uint(f);
    return (u + 0x7fffu + ((u >> 16) & 1u)) >> 16;
}
__global__ void scale_kernel(const float* __restrict__ x, const float* __restrict__ inv,
                             unsigned* __restrict__ xnb4) {
    int i = blockIdx.x * blockDim.x + threadIdx.x;  // 0 .. NN*16-1
    if (i >= NN * 16) return;
    int row = i >> 4;
    float w = inv[row];
    const float4* src = (const float4*)(x + (size_t)i * 8);
    float4 a = src[0], bq = src[1];
    uint4 o;
    o.x = bf16_rne(a.x * w)  | (bf16_rne(a.y * w) << 16);
    o.y = bf16_rne(a.z * w)  | (bf16_rne(a.w * w) << 16);
    o.z = bf16_rne(bq.x * w) | (bf16_rne(bq.y * w) << 16);
    o.w = bf16_rne(bq.z * w) | (bf16_rne(bq.w * w) << 16);
    ((uint4*)xnb4)[i] = o;
}

// ---------------- gather: out[n] = inv[n]*(xnb[n] + sum_s xnb[s]) ----------------
// one wave per node; lanes 0-31 even edges, 32-63 odd; each lane owns 4 cols (8B bf16)
// 8 rows in flight per half-wave (16 per wave) to raise MLP
#define ACC2(u) do { \
    ax += __uint_as_float((u).x << 16); \
    ay += __uint_as_float((u).x & 0xffff0000u); \
    az += __uint_as_float((u).y << 16); \
    aw += __uint_as_float((u).y & 0xffff0000u); } while (0)

__global__ __launch_bounds__(256) void gather_kernel(const unsigned* __restrict__ xnb,
                                                     const float* __restrict__ inv,
                                                     const int* __restrict__ off,
                                                     const int* __restrict__ cnt,
                                                     const unsigned short* __restrict__ csr,
                                                     float* __restrict__ out) {
    int wid = (blockIdx.x * blockDim.x + threadIdx.x) >> 6;
    if (wid >= NN) return;
    int lane = threadIdx.x & 63;
    int half = lane >> 5;
    int col4 = lane & 31;  // owns cols 4*col4 .. 4*col4+3 (one uint2)

    float ax = 0.f, ay = 0.f, az = 0.f, aw = 0.f;
    const uint2* xb = (const uint2*)xnb;  // 32 uint2 per row
    if (half == 0) {
        uint2 u = xb[(size_t)wid * 32 + col4];
        ACC2(u);
    }
    int n = cnt[wid];
    const unsigned short* row = csr + off[wid];
    int i = half;
    for (; i + 14 < n; i += 16) {
        int s0 = row[i],      s1 = row[i + 2],  s2 = row[i + 4],  s3 = row[i + 6];
        int s4 = row[i + 8],  s5 = row[i + 10], s6 = row[i + 12], s7 = row[i + 14];
        uint2 u0 = xb[(size_t)s0 * 32 + col4];
        uint2 u1 = xb[(size_t)s1 * 32 + col4];
        uint2 u2 = xb[(size_t)s2 * 32 + col4];
        uint2 u3 = xb[(size_t)s3 * 32 + col4];
        uint2 u4 = xb[(size_t)s4 * 32 + col4];
        uint2 u5 = xb[(size_t)s5 * 32 + col4];
        uint2 u6 = xb[(size_t)s6 * 32 + col4];
        uint2 u7 = xb[(size_t)s7 * 32 + col4];
        ACC2(u0); ACC2(u1); ACC2(u2); ACC2(u3);
        ACC2(u4); ACC2(u5); ACC2(u6); ACC2(u7);
    }
    for (; i + 6 < n; i += 8) {
        int s0 = row[i], s1 = row[i + 2], s2 = row[i + 4], s3 = row[i + 6];
        uint2 u0 = xb[(size_t)s0 * 32 + col4];
        uint2 u1 = xb[(size_t)s1 * 32 + col4];
        uint2 u2 = xb[(size_t)s2 * 32 + col4];
        uint2 u3 = xb[(size_t)s3 * 32 + col4];
        ACC2(u0); ACC2(u1); ACC2(u2); ACC2(u3);
    }
    for (; i < n; i += 2) {
        int s = row[i];
        uint2 u = xb[(size_t)s * 32 + col4];
        ACC2(u);
    }
    ax += __shfl_xor(ax, 32, 64);
    ay += __shfl_xor(ay, 32, 64);
    az += __shfl_xor(az, 32, 64);
    aw += __shfl_xor(aw, 32, 64);
    if (half == 0) {
        float wn = inv[wid];
        float4 o;
        o.x = ax * wn; o.y = ay * wn; o.z = az * wn; o.w = aw * wn;
        ((float4*)(out + (size_t)wid * D))[col4] = o;
    }
}

// ---------------- out[r][c] = h[r][:] . Wt[:][c] + b[c]  (in-place in io) ----------------
__global__ __launch_bounds__(256) void gemm_kernel(float* io, const float* __restrict__ Wt,
                                                   const float* __restrict__ b) {
    __shared__ float h[RPB][D];
    int r0 = blockIdx.x * RPB;

    const float4* src4 = (const float4*)(io + (size_t)r0 * D);
    for (int t = threadIdx.x; t < RPB * D / 4; t += 256) {
        ((float4*)h)[t] = src4[t];
    }
    __syncthreads();

    int c = threadIdx.x & 127;
    int rh = threadIdx.x >> 7;  // 0 or 1 -> rows rh*20 .. rh*20+19
    float acc[20];
#pragma unroll
    for (int j = 0; j < 20; ++j) acc[j] = 0.0f;

    for (int k0 = 0; k0 < D; k0 += 4) {
        float w0 = Wt[(k0 + 0) * D + c];
        float w1 = Wt[(k0 + 1) * D + c];
        float w2 = Wt[(k0 + 2) * D + c];
        float w3 = Wt[(k0 + 3) * D + c];
#pragma unroll
        for (int j = 0; j < 20; ++j) {
            float4 hv = *(const float4*)&h[rh * 20 + j][k0];  // LDS broadcast, b128
            acc[j] += hv.x * w0 + hv.y * w1 + hv.z * w2 + hv.w * w3;
        }
    }

    float bc = b[c];
#pragma unroll
    for (int j = 0; j < 20; ++j) {
        io[(size_t)(r0 + rh * 20 + j) * D + c] = acc[j] + bc;
    }
}

extern "C" void kernel_launch(void* const* d_in, const int* in_sizes, int n_in,
                              void* d_out, int out_size, void* d_ws, size_t ws_size,
                              hipStream_t stream) {
    const float* x  = (const float*)d_in[0];
    const int*   ei = (const int*)d_in[1];
    const float* W  = (const float*)d_in[2];
    const float* b  = (const float*)d_in[3];
    float* out = (float*)d_out;

    char* ws = (char*)d_ws;
    float*          inv  = (float*)         (ws + WS_INV);
    int*            cnt  = (int*)           (ws + WS_CNT);
    int*            off  = (int*)           (ws + WS_OFF);
    int*            bsum = (int*)           (ws + WS_BSUM);
    float*          Wt   = (float*)         (ws + WS_WT);
    int*            pdst = (int*)           (ws + WS_PDST);
    unsigned short* psrc = (unsigned short*)(ws + WS_PSRC);
    unsigned short* csr  = (unsigned short*)(ws + WS_CSR);
    unsigned*       xnb  = (unsigned*)      (ws + WS_XNB);  // overlays pdst AFTER fill_sorted

    fused_pre<<<208, 1024, 0, stream>>>(ei, W, psrc, pdst, Wt);
    reduce_both<<<(NN + 255) / 256, 256, 0, stream>>>(psrc, pdst, inv, cnt);
    scan_blocks<<<NB, 1024, 0, stream>>>(cnt, off, bsum);
    scan_chunks<<<(NN + 255) / 256, 256, 0, stream>>>(pdst, off, bsum);
    fill_sorted<<<NR * NC2, 1024, 0, stream>>>(ei, pdst, csr);
    scale_kernel<<<(NN * 16 + 255) / 256, 256, 0, stream>>>(x, inv, xnb);
    gather_kernel<<<(NN * 64 + 255) / 256, 256, 0, stream>>>(xnb, inv, off, cnt, csr, out);
    gemm_kernel<<<NN / RPB, 256, 0, stream>>>(out, Wt, b);
}

// Round 10
// 164.672 us; speedup vs baseline: 1.0819x; 1.0137x over previous
//
#include <hip/hip_runtime.h>

#define NN 50000
#define NE 1600000
#define D 128
#define RPB 40       // rows per block in the GEMM epilogue (50000/40 = 1250 blocks)
#define NRS 4        // key ranges (node-id partitions)
#define RNG 12500    // NN / NRS keys per range (50 KB LDS per histogram)
#define NC 32        // src edge chunks (CHUNK = 50000)
#define CHUNK 50000
#define NC2 64       // dst edge chunks (CHUNK2 = 25000)
#define CHUNK2 25000
#define NBS 196      // reduce_scan blocks = ceil(NN/256)

// ---- workspace layout (bytes), total 19,879,936 (proven budget) ----
#define WS_INV  0         // float NN
#define WS_CNT  204800    // int NN   (dst degree)
#define WS_OFF  409600    // int NN   (CSR offsets)
#define WS_BSUM 610304    // int NBS (fits in 4096 B gap)
#define WS_WT   614400    // float 128*128
#define WS_PDST 679936    // int NN*NC2 = 12.8 MB (dst counts -> absolute bases)
#define WS_PSRC 13479936  // ushort NN*NC = 3.2 MB (src counts)
#define WS_CSR  16679936  // ushort NE = 3.2 MB
#define WS_XNB  679936    // u32 NN*32 = 12.8 MB, OVERWRITES pdst after fill_sorted

// ---------------- fused: src hist (128 blks) + dst hist (256 blks) + W transpose (16 blks) ----------------
__global__ __launch_bounds__(1024) void fused_pre(const int* __restrict__ ei,
                                                  const float* __restrict__ W,
                                                  unsigned short* __restrict__ psrc,
                                                  int* __restrict__ pdst,
                                                  float* __restrict__ Wt) {
    __shared__ int h[RNG];
    int bid = blockIdx.x;
    if (bid < 128) {
        // src histogram: r = bid>>5 in [0,4), chunk c = bid&31 of CHUNK edges
        int r = bid >> 5, c = bid & 31;
        int lo = r * RNG;
        for (int j = threadIdx.x; j < RNG; j += 1024) h[j] = 0;
        __syncthreads();
        const int* s = ei + c * CHUNK;
        for (int i = threadIdx.x; i < CHUNK; i += 1024) {
            int k = s[i] - lo;
            if ((unsigned)k < RNG) atomicAdd(&h[k], 1);
        }
        __syncthreads();
        unsigned short* p = psrc + (size_t)bid * RNG;
        for (int j = threadIdx.x; j < RNG; j += 1024) p[j] = (unsigned short)h[j];
    } else if (bid < 384) {
        // dst per-chunk counts: b2 in [0,256), r = b2>>6 in [0,4), chunk c = b2&63
        int b2 = bid - 128;
        int r = b2 >> 6, c = b2 & 63;
        int lo = r * RNG;
        for (int j = threadIdx.x; j < RNG; j += 1024) h[j] = 0;
        __syncthreads();
        const int* d = ei + NE + c * CHUNK2;
        for (int i = threadIdx.x; i < CHUNK2; i += 1024) {
            int k = d[i] - lo;
            if ((unsigned)k < RNG) atomicAdd(&h[k], 1);
        }
        __syncthreads();
        int* p = pdst + (size_t)b2 * RNG;
        for (int j = threadIdx.x; j < RNG; j += 1024) p[j] = h[j];
    } else {
        // transpose W: 16 blocks x 1024 threads = 16384 elements
        int i = (bid - 384) * 1024 + threadIdx.x;
        int c = i >> 7, k = i & 127;
        Wt[k * D + c] = W[i];
    }
}

// ---------------- fused: inv/cnt reduction + per-block exclusive scan ----------------
// 196 blocks x 256 threads; block b owns nodes [b*256, b*256+256)
__global__ __launch_bounds__(256) void reduce_scan(const unsigned short* __restrict__ psrc,
                                                   const int* __restrict__ pdst,
                                                   float* __restrict__ inv,
                                                   int* __restrict__ cnt,
                                                   int* __restrict__ off,
                                                   int* __restrict__ bsum) {
    __shared__ int sh[256];
    int tid = threadIdx.x;
    int k = blockIdx.x * 256 + tid;
    int t = 0;
    if (k < NN) {
        int r = k / RNG, j = k - r * RNG;
        size_t bs = (size_t)(r * NC) * RNG + j;
        int s = 0;
#pragma unroll 8
        for (int c = 0; c < NC; ++c) s += psrc[bs + (size_t)c * RNG];
        size_t bd = (size_t)(r * NC2) * RNG + j;
#pragma unroll 8
        for (int c = 0; c < NC2; ++c) t += pdst[bd + (size_t)c * RNG];
        inv[k] = rsqrtf((float)s + 1.0f);
        cnt[k] = t;
    }
    sh[tid] = t;
    __syncthreads();
    for (int d = 1; d < 256; d <<= 1) {
        int v = (tid >= d) ? sh[tid - d] : 0;
        __syncthreads();
        sh[tid] += v;
        __syncthreads();
    }
    if (k < NN) off[k] = sh[tid] - t;  // exclusive within block
    if (tid == 255) bsum[blockIdx.x] = sh[255];
}

// ---------------- add block base; pdst counts -> absolute CSR bases ----------------
__global__ void scan_chunks(int* __restrict__ pdst, int* __restrict__ off,
                            const int* __restrict__ bsum) {
    int k = blockIdx.x * blockDim.x + threadIdx.x;
    if (k >= NN) return;
    int bi = k >> 8;
    int top = 0;
    for (int c = 0; c < bi; ++c) top += bsum[c];  // <=195 L2-broadcast loads
    int run = off[k] + top;
    off[k] = run;  // final CSR offset
    int r = k / RNG, j = k - r * RNG;
    size_t base = (size_t)(r * NC2) * RNG + j;
#pragma unroll 8
    for (int c = 0; c < NC2; ++c) {
        size_t p = base + (size_t)c * RNG;
        int v = pdst[p];
        pdst[p] = run;
        run += v;
    }
}

// ---------------- place edges: LDS cursor atomics only, plain ushort CSR stores ----------------
__global__ __launch_bounds__(1024) void fill_sorted(const int* __restrict__ ei,
                                                    const int* __restrict__ bases,
                                                    unsigned short* __restrict__ csr) {
    __shared__ int cur[RNG];
    int r = blockIdx.x >> 6, c = blockIdx.x & 63;
    int lo = r * RNG;
    const int* bslice = bases + (size_t)blockIdx.x * RNG;
    for (int j = threadIdx.x; j < RNG; j += 1024) cur[j] = bslice[j];
    __syncthreads();
    const int* s = ei + c * CHUNK2;
    const int* d = ei + NE + c * CHUNK2;
    for (int i = threadIdx.x; i < CHUNK2; i += 1024) {
        int kd = d[i] - lo;
        if ((unsigned)kd < RNG) {
            int pos = atomicAdd(&cur[kd], 1);
            csr[pos] = (unsigned short)s[i];
        }
    }
}

// ---------------- xnb[n][c] = bf16_rne(x[n][c] * inv[n]), packed 2/u32 ----------------
__device__ __forceinline__ unsigned bf16_rne(float f) {
    unsigned u = __float_as_uint(f);
    return (u + 0x7fffu + ((u >> 16) & 1u)) >> 16;
}
__global__ void scale_kernel(const float* __restrict__ x, const float* __restrict__ inv,
                             unsigned* __restrict__ xnb4) {
    int i = blockIdx.x * blockDim.x + threadIdx.x;  // 0 .. NN*16-1
    if (i >= NN * 16) return;
    int row = i >> 4;
    float w = inv[row];
    const float4* src = (const float4*)(x + (size_t)i * 8);
    float4 a = src[0], bq = src[1];
    uint4 o;
    o.x = bf16_rne(a.x * w)  | (bf16_rne(a.y * w) << 16);
    o.y = bf16_rne(a.z * w)  | (bf16_rne(a.w * w) << 16);
    o.z = bf16_rne(bq.x * w) | (bf16_rne(bq.y * w) << 16);
    o.w = bf16_rne(bq.z * w) | (bf16_rne(bq.w * w) << 16);
    ((uint4*)xnb4)[i] = o;
}

// ---------------- gather: out[n] = inv[n]*(xnb[n] + sum_s xnb[s]) ----------------
// one wave per node; lanes 0-31 even edges, 32-63 odd; each lane owns 4 cols (8B bf16)
#define ACC2(u) do { \
    ax += __uint_as_float((u).x << 16); \
    ay += __uint_as_float((u).x & 0xffff0000u); \
    az += __uint_as_float((u).y << 16); \
    aw += __uint_as_float((u).y & 0xffff0000u); } while (0)

__global__ __launch_bounds__(256) void gather_kernel(const unsigned* __restrict__ xnb,
                                                     const float* __restrict__ inv,
                                                     const int* __restrict__ off,
                                                     const int* __restrict__ cnt,
                                                     const unsigned short* __restrict__ csr,
                                                     float* __restrict__ out) {
    int wid = (blockIdx.x * blockDim.x + threadIdx.x) >> 6;
    if (wid >= NN) return;
    int lane = threadIdx.x & 63;
    int half = lane >> 5;
    int col4 = lane & 31;  // owns cols 4*col4 .. 4*col4+3 (one uint2)

    float ax = 0.f, ay = 0.f, az = 0.f, aw = 0.f;
    const uint2* xb = (const uint2*)xnb;  // 32 uint2 per row
    if (half == 0) {
        uint2 u = xb[(size_t)wid * 32 + col4];
        ACC2(u);
    }
    int n = cnt[wid];
    const unsigned short* row = csr + off[wid];
    int i = half;
    for (; i + 14 < n; i += 16) {
        int s0 = row[i],      s1 = row[i + 2],  s2 = row[i + 4],  s3 = row[i + 6];
        int s4 = row[i + 8],  s5 = row[i + 10], s6 = row[i + 12], s7 = row[i + 14];
        uint2 u0 = xb[(size_t)s0 * 32 + col4];
        uint2 u1 = xb[(size_t)s1 * 32 + col4];
        uint2 u2 = xb[(size_t)s2 * 32 + col4];
        uint2 u3 = xb[(size_t)s3 * 32 + col4];
        uint2 u4 = xb[(size_t)s4 * 32 + col4];
        uint2 u5 = xb[(size_t)s5 * 32 + col4];
        uint2 u6 = xb[(size_t)s6 * 32 + col4];
        uint2 u7 = xb[(size_t)s7 * 32 + col4];
        ACC2(u0); ACC2(u1); ACC2(u2); ACC2(u3);
        ACC2(u4); ACC2(u5); ACC2(u6); ACC2(u7);
    }
    for (; i + 6 < n; i += 8) {
        int s0 = row[i], s1 = row[i + 2], s2 = row[i + 4], s3 = row[i + 6];
        uint2 u0 = xb[(size_t)s0 * 32 + col4];
        uint2 u1 = xb[(size_t)s1 * 32 + col4];
        uint2 u2 = xb[(size_t)s2 * 32 + col4];
        uint2 u3 = xb[(size_t)s3 * 32 + col4];
        ACC2(u0); ACC2(u1); ACC2(u2); ACC2(u3);
    }
    for (; i < n; i += 2) {
        int s = row[i];
        uint2 u = xb[(size_t)s * 32 + col4];
        ACC2(u);
    }
    ax += __shfl_xor(ax, 32, 64);
    ay += __shfl_xor(ay, 32, 64);
    az += __shfl_xor(az, 32, 64);
    aw += __shfl_xor(aw, 32, 64);
    if (half == 0) {
        float wn = inv[wid];
        float4 o;
        o.x = ax * wn; o.y = ay * wn; o.z = az * wn; o.w = aw * wn;
        ((float4*)(out + (size_t)wid * D))[col4] = o;
    }
}

// ---------------- out[r][c] = h[r][:] . Wt[:][c] + b[c]  (in-place in io) ----------------
__global__ __launch_bounds__(256) void gemm_kernel(float* io, const float* __restrict__ Wt,
                                                   const float* __restrict__ b) {
    __shared__ float h[RPB][D];
    int r0 = blockIdx.x * RPB;

    const float4* src4 = (const float4*)(io + (size_t)r0 * D);
    for (int t = threadIdx.x; t < RPB * D / 4; t += 256) {
        ((float4*)h)[t] = src4[t];
    }
    __syncthreads();

    int c = threadIdx.x & 127;
    int rh = threadIdx.x >> 7;  // 0 or 1 -> rows rh*20 .. rh*20+19
    float acc[20];
#pragma unroll
    for (int j = 0; j < 20; ++j) acc[j] = 0.0f;

    for (int k0 = 0; k0 < D; k0 += 4) {
        float w0 = Wt[(k0 + 0) * D + c];
        float w1 = Wt[(k0 + 1) * D + c];
        float w2 = Wt[(k0 + 2) * D + c];
        float w3 = Wt[(k0 + 3) * D + c];
#pragma unroll
        for (int j = 0; j < 20; ++j) {
            float4 hv = *(const float4*)&h[rh * 20 + j][k0];  // LDS broadcast, b128
            acc[j] += hv.x * w0 + hv.y * w1 + hv.z * w2 + hv.w * w3;
        }
    }

    float bc = b[c];
#pragma unroll
    for (int j = 0; j < 20; ++j) {
        io[(size_t)(r0 + rh * 20 + j) * D + c] = acc[j] + bc;
    }
}

extern "C" void kernel_launch(void* const* d_in, const int* in_sizes, int n_in,
                              void* d_out, int out_size, void* d_ws, size_t ws_size,
                              hipStream_t stream) {
    const float* x  = (const float*)d_in[0];
    const int*   ei = (const int*)d_in[1];
    const float* W  = (const float*)d_in[2];
    const float* b  = (const float*)d_in[3];
    float* out = (float*)d_out;

    char* ws = (char*)d_ws;
    float*          inv  = (float*)         (ws + WS_INV);
    int*            cnt  = (int*)           (ws + WS_CNT);
    int*            off  = (int*)           (ws + WS_OFF);
    int*            bsum = (int*)           (ws + WS_BSUM);
    float*          Wt   = (float*)         (ws + WS_WT);
    int*            pdst = (int*)           (ws + WS_PDST);
    unsigned short* psrc = (unsigned short*)(ws + WS_PSRC);
    unsigned short* csr  = (unsigned short*)(ws + WS_CSR);
    unsigned*       xnb  = (unsigned*)      (ws + WS_XNB);  // overlays pdst AFTER fill_sorted

    fused_pre<<<400, 1024, 0, stream>>>(ei, W, psrc, pdst, Wt);
    reduce_scan<<<NBS, 256, 0, stream>>>(psrc, pdst, inv, cnt, off, bsum);
    scan_chunks<<<(NN + 255) / 256, 256, 0, stream>>>(pdst, off, bsum);
    fill_sorted<<<NRS * NC2, 1024, 0, stream>>>(ei, pdst, csr);
    scale_kernel<<<(NN * 16 + 255) / 256, 256, 0, stream>>>(x, inv, xnb);
    gather_kernel<<<(NN * 64 + 255) / 256, 256, 0, stream>>>(xnb, inv, off, cnt, csr, out);
    gemm_kernel<<<NN / RPB, 256, 0, stream>>>(out, Wt, b);
}